// Round 1
// baseline (169.428 us; speedup 1.0000x reference)
//
#include <hip/hip_runtime.h>
#include <math.h>

#define MEMSZ 16384
#define NCTX  16453   // MEM + 5 + 64

// ---- soft-gate helpers (exact float32 replication of the reference) ----
__device__ __forceinline__ float sigmoidf_(float x) {
    return 1.0f / (1.0f + __expf(-x));
}
__device__ __forceinline__ float siluf_(float x) {
    return x * sigmoidf_(x);
}
// silu_threshold(x, 20) = (silu(20x+10) - silu(20x-10)) / 20
__device__ __forceinline__ float silu_thr(float x) {
    float d = 20.0f * x;
    return (siluf_(d + 10.0f) - siluf_(d - 10.0f)) * 0.05f;
}
// eq_gate(a,b) = st(diff+0.5) * st(-diff+0.5)
__device__ __forceinline__ float eq_gate_d(float diff) {
    return silu_thr(diff + 0.5f) * silu_thr(0.5f - diff);
}

// ---- bulk copy: memory -> d_out ----
__global__ void copy_kernel(const float4* __restrict__ src,
                            float4* __restrict__ dst, int n4) {
    int i = blockIdx.x * blockDim.x + threadIdx.x;
    if (i < n4) dst[i] = src[i];
}

// ---- per-row simulator: 1 thread per batch row, in place on d_out ----
__global__ void sim_kernel(float* __restrict__ mem,          // [B, MEMSZ] (d_out, pre-copied)
                           const float* __restrict__ outp,   // [B, 64]
                           const float* __restrict__ ax_in,  // [B]
                           const int* __restrict__ pc_in,    // [B]
                           const int* __restrict__ sp_in,    // [B]
                           const int* __restrict__ bp_in,    // [B]
                           const int* __restrict__ ol_in,    // [B]
                           const int* __restrict__ nstep,    // [1]
                           int B) {
    int b = blockIdx.x * blockDim.x + threadIdx.x;
    if (b >= B) return;

    float* __restrict__ mrow = mem + (size_t)b * MEMSZ;
    const float* __restrict__ orow = outp + (size_t)b * 64;

    float pc  = (float)pc_in[b];
    float sp  = (float)sp_in[b];
    float bp  = (float)bp_in[b];
    float ax  = ax_in[b];
    float olf = (float)ol_in[b];
    int   T   = nstep[0];

    // OP_VALS order: IMM,LEA,ADD,SUB,MUL,DIV,MOD,SHL,SHR,EQ,NE,LT,GT,LE,GE
    const float opv[15] = {1.f, 2.f, 9.f, 10.f, 11.f, 12.f, 13.f, 14.f, 15.f,
                           3.f, 4.f, 5.f, 6.f, 7.f, 8.f};

    for (int t = 0; t < T; ++t) {
        // ---------- inst = attend(context, pc) ----------
        float a1 = fminf(fmaxf(pc, 0.0f), (float)(NCTX - 1));
        int ai = (int)a1;
        float inst;
        if (ai < MEMSZ) {
            inst = mrow[ai];
        } else {
            int r = ai - MEMSZ;
            float cv = (r == 0) ? pc
                     : (r == 1) ? sp
                     : (r == 2) ? bp
                     : (r == 3) ? ax
                     : (r == 4) ? olf
                                : orow[r - 5];
            // softmax ties 0.5/0.5 between slot ai and memory slot ai-MEM
            inst = 0.5f * (cv + mrow[ai - MEMSZ]);
        }
        float imm = floorf(inst * (1.0f / 256.0f));
        float opc = inst - imm * 256.0f;

        // ---------- stack_top = attend(context, sp) ----------
        float a2 = fminf(fmaxf(sp, 0.0f), (float)(NCTX - 1));
        int si = (int)a2;
        int target = (si < MEMSZ) ? si : (si - MEMSZ);
        float mtv = mrow[target];          // current memory value at scatter target
        float stv, wfac;
        if (si < MEMSZ) {
            stv = mtv;
            wfac = 1.0f;
        } else {
            int r = si - MEMSZ;
            float cv = (r == 0) ? pc
                     : (r == 1) ? sp
                     : (r == 2) ? bp
                     : (r == 3) ? ax
                     : (r == 4) ? olf
                                : orow[r - 5];
            stv = 0.5f * (cv + mtv);
            wfac = 0.5f;
        }

        // ---------- experts ----------
        float a = stv, bv = ax;
        float safeb = (fabsf(bv) < 1e-6f) ? 1e-6f : bv;
        float dv = a / safeb;
        float md = a - safeb * floorf(dv);
        float sh = fminf(fmaxf(bv, 0.0f), 31.0f);
        float eq = eq_gate_d(a - bv);
        float lt = sigmoidf_(20.0f * (bv - a - 0.5f));
        float gt = sigmoidf_(20.0f * (a - bv - 0.5f));
        float outs[15] = {
            imm,                 // IMM
            bp + imm,            // LEA
            a + bv,              // ADD
            a - bv,              // SUB
            a * bv,              // MUL
            dv,                  // DIV
            md,                  // MOD
            a * exp2f(sh),       // SHL
            a * exp2f(-sh),      // SHR
            eq,                  // EQ
            1.0f - eq,           // NE
            lt,                  // LT
            gt,                  // GT
            1.0f - gt,           // LE
            1.0f - lt            // GE
        };

        float gsum = 0.0f, acc = 0.0f, pop = 0.0f;
#pragma unroll
        for (int j = 0; j < 15; ++j) {
            float g = eq_gate_d(opc - opv[j]);
            gsum += g;
            acc += g * outs[j];
            if (j >= 2) pop += g;   // POP_MASK: everything except IMM, LEA
        }
        float nax = acc + (1.0f - gsum) * ax;

        // ---------- soft scatter (one-hot / half-weight) ----------
        mrow[target] = mtv + pop * wfac * (nax - mtv);

        sp = sp + 8.0f * pop;
        pc = pc + 8.0f;
        ax = nax;
    }
}

extern "C" void kernel_launch(void* const* d_in, const int* in_sizes, int n_in,
                              void* d_out, int out_size, void* d_ws, size_t ws_size,
                              hipStream_t stream) {
    const float* memory = (const float*)d_in[0];
    const float* output = (const float*)d_in[1];
    const float* ax     = (const float*)d_in[2];
    const int*   pc     = (const int*)d_in[3];
    const int*   sp     = (const int*)d_in[4];
    const int*   bp     = (const int*)d_in[5];
    const int*   ol     = (const int*)d_in[6];
    const int*   ns     = (const int*)d_in[7];

    int B = in_sizes[0] / MEMSZ;
    int n = B * MEMSZ;
    int n4 = n / 4;

    float* out = (float*)d_out;

    hipLaunchKernelGGL(copy_kernel, dim3((n4 + 255) / 256), dim3(256), 0, stream,
                       (const float4*)memory, (float4*)out, n4);
    hipLaunchKernelGGL(sim_kernel, dim3((B + 255) / 256), dim3(256), 0, stream,
                       out, output, ax, pc, sp, bp, ol, ns, B);
}